// Round 1
// baseline (310.103 us; speedup 1.0000x reference)
//
#include <hip/hip_runtime.h>

// ---------- problem constants ----------
#define BB   4096   // batch
#define IN_  256
#define NN   128
#define KK   4
#define JJ   64
#define NG   512        // N*K
#define WS_  131072     // IN*NG
#define PER  131584     // WS_+NG
#define TP   263168     // 2*PER
#define OUTD 128

typedef __attribute__((ext_vector_type(8))) short short8;
typedef __attribute__((ext_vector_type(4))) float f32x4;

__device__ __forceinline__ unsigned short f2bf(float f){
  unsigned u = __float_as_uint(f);
  return (unsigned short)((u + 0x7fffu + ((u >> 16) & 1u)) >> 16);
}

// ---------- 1. f32 -> bf16 convert: x, Wb0, Wb1 ----------
#define XE  (4096u*256u)            // 1048576
#define W0E (XE + 8388608u)         // + 128*4*64*256
#define W1E (W0E + 4194304u)        // + 128*4*64*128

__global__ void k_convert(const float* __restrict__ x,
                          const float* __restrict__ w0,
                          const float* __restrict__ w1,
                          unsigned short* __restrict__ xb,
                          unsigned short* __restrict__ w0b,
                          unsigned short* __restrict__ w1b){
  size_t i = ((size_t)blockIdx.x*256 + threadIdx.x)*4;
  if (i >= W1E) return;
  const float* s; unsigned short* d; size_t off;
  if (i < XE)       { s = x;  d = xb;  off = i; }
  else if (i < W0E) { s = w0; d = w0b; off = i - XE; }
  else              { s = w1; d = w1b; off = i - W0E; }
  float4 v = *(const float4*)(s + off);
  ushort4 o;
  o.x = f2bf(v.x); o.y = f2bf(v.y); o.z = f2bf(v.z); o.w = f2bf(v.w);
  *(ushort4*)(d + off) = o;
}

// ---------- 2. hypernet MLP (context -> hv2[64]) ----------
__global__ void k_hyper(const float* __restrict__ ctx,
                        const float* __restrict__ h1w, const float* __restrict__ h1b,
                        const float* __restrict__ h2w, const float* __restrict__ h2b,
                        float* __restrict__ hv2){
  __shared__ float s1[32];
  int t = threadIdx.x;
  if (t < 32){
    float a = h1b[t];
    #pragma unroll 8
    for (int i = 0; i < 64; ++i) a += ctx[i]*h1w[t*64+i];
    s1[t] = fmaxf(a, 0.f);
  }
  __syncthreads();
  float a = h2b[t];
  #pragma unroll 8
  for (int i = 0; i < 32; ++i) a += s1[i]*h2w[t*32+i];
  hv2[t] = fmaxf(a, 0.f);
}

// ---------- 3. gw = hv2 @ h3w.T + h3b  ->  Wg_bf (1024x256 bf16), bg (1024 f32) ----------
// 4 lanes per row; 64 rows per 256-thread block.
__global__ void k_gw(const float* __restrict__ hv2,
                     const float* __restrict__ h3w, const float* __restrict__ h3b,
                     unsigned short* __restrict__ Wg_bf, float* __restrict__ bg){
  int t = threadIdx.x;
  int r = blockIdx.x*64 + (t >> 2);
  int q = t & 3;
  const float4* row = (const float4*)(h3w + (size_t)r*64);
  float a = 0.f;
  #pragma unroll
  for (int i = 0; i < 4; ++i){
    float4 v = row[q*4 + i];
    float4 h = *(const float4*)(hv2 + q*16 + i*4);
    a += v.x*h.x + v.y*h.y + v.z*h.z + v.w*h.w;
  }
  a += __shfl_xor(a, 1);
  a += __shfl_xor(a, 2);
  if (q == 0){
    a += h3b[r];
    if (r < WS_)          Wg_bf[r] = f2bf(a);                    // layer0 Wg rows 0..511
    else if (r < PER)     bg[r - WS_] = a;                       // layer0 bg
    else if (r < PER+WS_) Wg_bf[WS_ + (r - PER)] = f2bf(a);      // layer1 Wg rows 512..1023
    else                  bg[512 + (r - (PER+WS_))] = a;         // layer1 bg
  }
}

// ---------- 4. gates GEMM: G_T[m(1024)][b(4096)] = sigmoid(Wg[m]·x[b] + bg[m]) ----------
// M-tile 128 (gate rows, staged in As), N-tile 256 (batch rows, staged in Bs), BK=64.
__global__ __launch_bounds__(512, 1)
void k_gates(const unsigned short* __restrict__ Wg_bf,  // 1024 x 256
             const unsigned short* __restrict__ x_bf,   // 4096 x 256
             const float* __restrict__ bg,              // 1024
             float* __restrict__ GT){                    // 1024 x 4096
  __shared__ __align__(16) unsigned short As[128*64];
  __shared__ __align__(16) unsigned short Bs[256*64];
  const int tid  = threadIdx.x;
  const int lane = tid & 63;
  const int wid  = tid >> 6;
  const int wm = wid >> 2, wn = wid & 3;
  const int lrow = lane & 15, lk = lane >> 4;
  const int m0 = blockIdx.x*128;
  const int b0 = blockIdx.y*256;

  f32x4 zero = {0.f,0.f,0.f,0.f};
  f32x4 acc[4][4];
  #pragma unroll
  for (int i=0;i<4;++i)
    #pragma unroll
    for (int j=0;j<4;++j) acc[i][j] = zero;

  for (int kt = 0; kt < 256/64; ++kt){
    __syncthreads();
    #pragma unroll
    for (int i = 0; i < 2; ++i){            // A: 128x64 -> 1024 16B chunks
      int c = tid + i*512;
      int row = c >> 3, k8 = c & 7;
      uint4 v = *(const uint4*)(Wg_bf + (size_t)(m0+row)*256 + kt*64 + k8*8);
      int idx = (row*64 + k8*8) ^ ((row & 7) << 3);
      *(uint4*)(&As[idx]) = v;
    }
    #pragma unroll
    for (int i = 0; i < 4; ++i){            // B: 256x64 -> 2048 chunks
      int c = tid + i*512;
      int row = c >> 3, k8 = c & 7;
      uint4 v = *(const uint4*)(x_bf + (size_t)(b0+row)*256 + kt*64 + k8*8);
      int idx = (row*64 + k8*8) ^ ((row & 7) << 3);
      *(uint4*)(&Bs[idx]) = v;
    }
    __syncthreads();
    #pragma unroll
    for (int kk = 0; kk < 2; ++kk){
      short8 a[4], b[4];
      #pragma unroll
      for (int fm = 0; fm < 4; ++fm){
        int m = wm*64 + fm*16 + lrow;
        int idx = (m*64 + kk*32 + lk*8) ^ ((m & 7) << 3);
        a[fm] = *(const short8*)(&As[idx]);
      }
      #pragma unroll
      for (int fn = 0; fn < 4; ++fn){
        int r = wn*64 + fn*16 + lrow;
        int idx = (r*64 + kk*32 + lk*8) ^ ((r & 7) << 3);
        b[fn] = *(const short8*)(&Bs[idx]);
      }
      #pragma unroll
      for (int fm = 0; fm < 4; ++fm)
        #pragma unroll
        for (int fn = 0; fn < 4; ++fn)
          acc[fm][fn] = __builtin_amdgcn_mfma_f32_16x16x32_bf16(a[fm], b[fn], acc[fm][fn], 0, 0, 0);
    }
  }
  // epilogue: sigmoid, store transposed (row m, col b)
  #pragma unroll
  for (int fm = 0; fm < 4; ++fm){
    float4 bgv = *(const float4*)(bg + m0 + wm*64 + fm*16 + lk*4);
    float bga[4] = {bgv.x, bgv.y, bgv.z, bgv.w};
    #pragma unroll
    for (int reg = 0; reg < 4; ++reg){
      int m = m0 + wm*64 + fm*16 + lk*4 + reg;
      #pragma unroll
      for (int fn = 0; fn < 4; ++fn){
        int b = b0 + wn*64 + fn*16 + lrow;
        float z = acc[fm][fn][reg] + bga[reg];
        GT[(size_t)m*4096 + b] = 1.f/(1.f + __expf(-z));
      }
    }
  }
}

// ---------- 5/6. fused DANN layer ----------
// out[b,n] = sum_{k,j} relu(A[b]·Wb[n,k,j] + bb[n,k,j]) * gate[b,n,k] * Ws[n,k*64+j] + bs[n]
// block: 128 b-rows x 256 gemm-cols (= one n). 8 waves (2 wm x 4 wn); wn == k-group.
template<int KIN, int LAYER>
__global__ __launch_bounds__(512, 1)
void k_layer(const unsigned short* __restrict__ Abf,  // (4096, KIN) bf16
             const unsigned short* __restrict__ Wbf,  // (32768, KIN) bf16
             const float* __restrict__ bb,            // 32768
             const float* __restrict__ Ws,            // 128*256
             const float* __restrict__ bs,            // 128
             const float* __restrict__ GT,            // 1024 x 4096
             unsigned short* __restrict__ cur_bf,     // layer0 out (bf16, 4096x128)
             float* __restrict__ out1){               // layer1 out (f32, 4096x128)
  __shared__ __align__(16) unsigned short As[128*64];
  __shared__ __align__(16) unsigned short Bs[256*64];
  __shared__ float part[4][128];

  const int tid  = threadIdx.x;
  const int lane = tid & 63;
  const int wid  = tid >> 6;
  const int wm = wid >> 2, wn = wid & 3;
  const int lrow = lane & 15, lk = lane >> 4;
  const int n = blockIdx.y;
  const int bbase = blockIdx.x*128;

  f32x4 zero = {0.f,0.f,0.f,0.f};
  f32x4 acc[4][4];
  #pragma unroll
  for (int i=0;i<4;++i)
    #pragma unroll
    for (int j=0;j<4;++j) acc[i][j] = zero;

  for (int kt = 0; kt < KIN/64; ++kt){
    __syncthreads();
    #pragma unroll
    for (int i = 0; i < 2; ++i){            // A tile 128x64
      int c = tid + i*512;
      int row = c >> 3, k8 = c & 7;
      uint4 v = *(const uint4*)(Abf + (size_t)(bbase+row)*KIN + kt*64 + k8*8);
      int idx = (row*64 + k8*8) ^ ((row & 7) << 3);
      *(uint4*)(&As[idx]) = v;
    }
    #pragma unroll
    for (int i = 0; i < 4; ++i){            // B tile 256x64 (Wb rows n*256 .. n*256+255)
      int c = tid + i*512;
      int row = c >> 3, k8 = c & 7;
      uint4 v = *(const uint4*)(Wbf + (size_t)(n*256+row)*KIN + kt*64 + k8*8);
      int idx = (row*64 + k8*8) ^ ((row & 7) << 3);
      *(uint4*)(&Bs[idx]) = v;
    }
    __syncthreads();
    #pragma unroll
    for (int kk = 0; kk < 2; ++kk){
      short8 a[4], b[4];
      #pragma unroll
      for (int fm = 0; fm < 4; ++fm){
        int m = wm*64 + fm*16 + lrow;
        int idx = (m*64 + kk*32 + lk*8) ^ ((m & 7) << 3);
        a[fm] = *(const short8*)(&As[idx]);
      }
      #pragma unroll
      for (int fn = 0; fn < 4; ++fn){
        int r = wn*64 + fn*16 + lrow;
        int idx = (r*64 + kk*32 + lk*8) ^ ((r & 7) << 3);
        b[fn] = *(const short8*)(&Bs[idx]);
      }
      #pragma unroll
      for (int fm = 0; fm < 4; ++fm)
        #pragma unroll
        for (int fn = 0; fn < 4; ++fn)
          acc[fm][fn] = __builtin_amdgcn_mfma_f32_16x16x32_bf16(a[fm], b[fn], acc[fm][fn], 0, 0, 0);
    }
  }

  // ---- epilogue: relu(+bb) * gate * Ws, reduce 256 cols -> out[b,n] ----
  const int gidx = LAYER*512 + n*4 + wn;      // wn == k
  float bbv[4], wsv[4];
  #pragma unroll
  for (int fn = 0; fn < 4; ++fn){
    int c = wn*64 + fn*16 + lrow;
    bbv[fn] = bb[n*256 + c];
    wsv[fn] = Ws[n*256 + c];
  }
  #pragma unroll
  for (int fm = 0; fm < 4; ++fm){
    float4 g = *(const float4*)(GT + (size_t)gidx*4096 + bbase + wm*64 + fm*16 + lk*4);
    float gr[4] = {g.x, g.y, g.z, g.w};
    #pragma unroll
    for (int reg = 0; reg < 4; ++reg){
      float s = 0.f;
      #pragma unroll
      for (int fn = 0; fn < 4; ++fn)
        s += fmaxf(acc[fm][fn][reg] + bbv[fn], 0.f) * wsv[fn];
      s *= gr[reg];
      s += __shfl_xor(s, 1);
      s += __shfl_xor(s, 2);
      s += __shfl_xor(s, 4);
      s += __shfl_xor(s, 8);
      if (lrow == 0) part[wn][wm*64 + fm*16 + lk*4 + reg] = s;
    }
  }
  __syncthreads();
  if (tid < 128){
    float v = part[0][tid] + part[1][tid] + part[2][tid] + part[3][tid] + bs[n];
    if (LAYER == 0) cur_bf[(size_t)(bbase+tid)*128 + n] = f2bf(v);
    else            out1[(size_t)(bbase+tid)*128 + n] = v;
  }
}

// ---------- 7. final projection: out = cur1 @ Wout.T + bout ----------
__global__ void k_final(const float* __restrict__ out1, const float* __restrict__ Wout,
                        const float* __restrict__ bout, float* __restrict__ out){
  int t = blockIdx.x*256 + threadIdx.x;
  int b = t >> 7, o = t & 127;
  const float4* cr = (const float4*)(out1 + (size_t)b*128);
  const float4* wr = (const float4*)(Wout + (size_t)o*128);
  float a = 0.f;
  #pragma unroll
  for (int i = 0; i < 32; ++i){
    float4 c = cr[i], w = wr[i];
    a += c.x*w.x + c.y*w.y + c.z*w.z + c.w*w.w;
  }
  out[t] = a + bout[o];
}

// ---------- launch ----------
extern "C" void kernel_launch(void* const* d_in, const int* in_sizes, int n_in,
                              void* d_out, int out_size, void* d_ws, size_t ws_size,
                              hipStream_t stream){
  const float* x    = (const float*)d_in[0];
  const float* ctx  = (const float*)d_in[1];
  const float* Wb0  = (const float*)d_in[2];
  const float* bb0  = (const float*)d_in[3];
  const float* Ws0  = (const float*)d_in[4];
  const float* bs0  = (const float*)d_in[5];
  const float* Wb1  = (const float*)d_in[6];
  const float* bb1  = (const float*)d_in[7];
  const float* Ws1  = (const float*)d_in[8];
  const float* bs1  = (const float*)d_in[9];
  const float* Wout = (const float*)d_in[10];
  const float* bout = (const float*)d_in[11];
  const float* h1w  = (const float*)d_in[12];
  const float* h1b  = (const float*)d_in[13];
  const float* h2w  = (const float*)d_in[14];
  const float* h2b  = (const float*)d_in[15];
  const float* h3w  = (const float*)d_in[16];
  const float* h3b  = (const float*)d_in[17];
  float* out = (float*)d_out;

  char* ws = (char*)d_ws;
  size_t o = 0;
  unsigned short* x_bf  = (unsigned short*)(ws + o); o += (size_t)4096*256*2;
  unsigned short* W0b   = (unsigned short*)(ws + o); o += (size_t)8388608*2;
  unsigned short* W1b   = (unsigned short*)(ws + o); o += (size_t)4194304*2;
  unsigned short* Wg_bf = (unsigned short*)(ws + o); o += (size_t)1024*256*2;
  float* bg   = (float*)(ws + o); o += 1024*4;
  float* hv2  = (float*)(ws + o); o += 256;
  float* GT   = (float*)(ws + o); o += (size_t)1024*4096*4;
  unsigned short* cur_bf = (unsigned short*)(ws + o); o += (size_t)4096*128*2;
  float* out1 = (float*)(ws + o); o += (size_t)4096*128*4;

  k_convert<<<13312, 256, 0, stream>>>(x, Wb0, Wb1, x_bf, W0b, W1b);
  k_hyper<<<1, 64, 0, stream>>>(ctx, h1w, h1b, h2w, h2b, hv2);
  k_gw<<<4112, 256, 0, stream>>>(hv2, h3w, h3b, Wg_bf, bg);
  k_gates<<<dim3(8, 16), 512, 0, stream>>>(Wg_bf, x_bf, bg, GT);
  k_layer<256, 0><<<dim3(32, 128), 512, 0, stream>>>(x_bf, W0b, bb0, Ws0, bs0, GT, cur_bf, out1);
  k_layer<128, 1><<<dim3(32, 128), 512, 0, stream>>>(cur_bf, W1b, bb1, Ws1, bs1, GT, cur_bf, out1);
  k_final<<<2048, 256, 0, stream>>>(out1, Wout, bout, out);
}

// Round 2
// 306.359 us; speedup vs baseline: 1.0122x; 1.0122x over previous
//
#include <hip/hip_runtime.h>

// ---------- problem constants ----------
#define BB   4096   // batch
#define IN_  256
#define NN   128
#define KK   4
#define JJ   64
#define NG   512        // N*K
#define WS_  131072     // IN*NG
#define PER  131584     // WS_+NG
#define TP   263168     // 2*PER
#define OUTD 128

typedef __attribute__((ext_vector_type(8))) short short8;
typedef __attribute__((ext_vector_type(4))) float f32x4;

__device__ __forceinline__ unsigned short f2bf(float f){
  unsigned u = __float_as_uint(f);
  return (unsigned short)((u + 0x7fffu + ((u >> 16) & 1u)) >> 16);
}

__device__ __forceinline__ void gload16(const void* g, void* l){
  __builtin_amdgcn_global_load_lds((const __attribute__((address_space(1))) void*)g,
                                   (__attribute__((address_space(3))) void*)l, 16, 0, 0);
}

// ---------- 1. f32 -> bf16 convert: x, Wb0, Wb1 ----------
#define XE  (4096u*256u)            // 1048576
#define W0E (XE + 8388608u)         // + 128*4*64*256
#define W1E (W0E + 4194304u)        // + 128*4*64*128

__global__ void k_convert(const float* __restrict__ x,
                          const float* __restrict__ w0,
                          const float* __restrict__ w1,
                          unsigned short* __restrict__ xb,
                          unsigned short* __restrict__ w0b,
                          unsigned short* __restrict__ w1b){
  size_t i = ((size_t)blockIdx.x*256 + threadIdx.x)*4;
  if (i >= W1E) return;
  const float* s; unsigned short* d; size_t off;
  if (i < XE)       { s = x;  d = xb;  off = i; }
  else if (i < W0E) { s = w0; d = w0b; off = i - XE; }
  else              { s = w1; d = w1b; off = i - W0E; }
  float4 v = *(const float4*)(s + off);
  ushort4 o;
  o.x = f2bf(v.x); o.y = f2bf(v.y); o.z = f2bf(v.z); o.w = f2bf(v.w);
  *(ushort4*)(d + off) = o;
}

// ---------- 2. hypernet MLP (context -> hv2[64]) ----------
__global__ void k_hyper(const float* __restrict__ ctx,
                        const float* __restrict__ h1w, const float* __restrict__ h1b,
                        const float* __restrict__ h2w, const float* __restrict__ h2b,
                        float* __restrict__ hv2){
  __shared__ float s1[32];
  int t = threadIdx.x;
  if (t < 32){
    float a = h1b[t];
    #pragma unroll 8
    for (int i = 0; i < 64; ++i) a += ctx[i]*h1w[t*64+i];
    s1[t] = fmaxf(a, 0.f);
  }
  __syncthreads();
  float a = h2b[t];
  #pragma unroll 8
  for (int i = 0; i < 32; ++i) a += s1[i]*h2w[t*32+i];
  hv2[t] = fmaxf(a, 0.f);
}

// ---------- 3. gw = hv2 @ h3w.T + h3b  ->  Wg_bf (1024x256 bf16), bg (1024 f32) ----------
__global__ void k_gw(const float* __restrict__ hv2,
                     const float* __restrict__ h3w, const float* __restrict__ h3b,
                     unsigned short* __restrict__ Wg_bf, float* __restrict__ bg){
  int t = threadIdx.x;
  int r = blockIdx.x*64 + (t >> 2);
  int q = t & 3;
  const float4* row = (const float4*)(h3w + (size_t)r*64);
  float a = 0.f;
  #pragma unroll
  for (int i = 0; i < 4; ++i){
    float4 v = row[q*4 + i];
    float4 h = *(const float4*)(hv2 + q*16 + i*4);
    a += v.x*h.x + v.y*h.y + v.z*h.z + v.w*h.w;
  }
  a += __shfl_xor(a, 1);
  a += __shfl_xor(a, 2);
  if (q == 0){
    a += h3b[r];
    if (r < WS_)          Wg_bf[r] = f2bf(a);
    else if (r < PER)     bg[r - WS_] = a;
    else if (r < PER+WS_) Wg_bf[WS_ + (r - PER)] = f2bf(a);
    else                  bg[512 + (r - (PER+WS_))] = a;
  }
}

// ---------- 4. gates GEMM: G_T[m(1024)][b(4096)] = sigmoid(Wg[m]·x[b] + bg[m]) ----------
__global__ __launch_bounds__(512, 1)
void k_gates(const unsigned short* __restrict__ Wg_bf,  // 1024 x 256
             const unsigned short* __restrict__ x_bf,   // 4096 x 256
             const float* __restrict__ bg,              // 1024
             float* __restrict__ GT){                    // 1024 x 4096
  __shared__ __align__(16) unsigned short As[128*64];
  __shared__ __align__(16) unsigned short Bs[256*64];
  const int tid  = threadIdx.x;
  const int lane = tid & 63;
  const int wid  = tid >> 6;
  const int wm = wid >> 2, wn = wid & 3;
  const int lrow = lane & 15, lk = lane >> 4;
  const int m0 = blockIdx.x*128;
  const int b0 = blockIdx.y*256;

  f32x4 zero = {0.f,0.f,0.f,0.f};
  f32x4 acc[4][4];
  #pragma unroll
  for (int i=0;i<4;++i)
    #pragma unroll
    for (int j=0;j<4;++j) acc[i][j] = zero;

  for (int kt = 0; kt < 256/64; ++kt){
    __syncthreads();
    #pragma unroll
    for (int i = 0; i < 2; ++i){
      int c = tid + i*512;
      int row = c >> 3, k8 = c & 7;
      uint4 v = *(const uint4*)(Wg_bf + (size_t)(m0+row)*256 + kt*64 + k8*8);
      int idx = (row*64 + k8*8) ^ ((row & 7) << 3);
      *(uint4*)(&As[idx]) = v;
    }
    #pragma unroll
    for (int i = 0; i < 4; ++i){
      int c = tid + i*512;
      int row = c >> 3, k8 = c & 7;
      uint4 v = *(const uint4*)(x_bf + (size_t)(b0+row)*256 + kt*64 + k8*8);
      int idx = (row*64 + k8*8) ^ ((row & 7) << 3);
      *(uint4*)(&Bs[idx]) = v;
    }
    __syncthreads();
    #pragma unroll
    for (int kk = 0; kk < 2; ++kk){
      short8 a[4], b[4];
      #pragma unroll
      for (int fm = 0; fm < 4; ++fm){
        int m = wm*64 + fm*16 + lrow;
        int idx = (m*64 + kk*32 + lk*8) ^ ((m & 7) << 3);
        a[fm] = *(const short8*)(&As[idx]);
      }
      #pragma unroll
      for (int fn = 0; fn < 4; ++fn){
        int r = wn*64 + fn*16 + lrow;
        int idx = (r*64 + kk*32 + lk*8) ^ ((r & 7) << 3);
        b[fn] = *(const short8*)(&Bs[idx]);
      }
      #pragma unroll
      for (int fm = 0; fm < 4; ++fm)
        #pragma unroll
        for (int fn = 0; fn < 4; ++fn)
          acc[fm][fn] = __builtin_amdgcn_mfma_f32_16x16x32_bf16(a[fm], b[fn], acc[fm][fn], 0, 0, 0);
    }
  }
  #pragma unroll
  for (int fm = 0; fm < 4; ++fm){
    float4 bgv = *(const float4*)(bg + m0 + wm*64 + fm*16 + lk*4);
    float bga[4] = {bgv.x, bgv.y, bgv.z, bgv.w};
    #pragma unroll
    for (int reg = 0; reg < 4; ++reg){
      int m = m0 + wm*64 + fm*16 + lk*4 + reg;
      #pragma unroll
      for (int fn = 0; fn < 4; ++fn){
        int b = b0 + wn*64 + fn*16 + lrow;
        float z = acc[fm][fn][reg] + bga[reg];
        GT[(size_t)m*4096 + b] = 1.f/(1.f + __expf(-z));
      }
    }
  }
}

// ---------- 5/6. fused DANN layer ----------
// out[b,n] = sum_{k,j} relu(A[b]·Wb[n,k,j] + bb[n,k,j]) * gate[b,n,k] * Ws[n,k*64+j] + bs[n]
// 1D grid 4096 with XCD-bijective remap: xcd = id&7 owns n ≡ xcd (mod 8) ->
// 16 Wb slices (<=2.1 MB) stay L2-resident per XCD.
// Double-buffered LDS, global_load_lds (linear dest, pre-swizzled source),
// 2-phase prefetch: STAGE(next) -> MFMA(cur) -> vmcnt(0)+s_barrier.
template<int KIN, int LAYER>
__global__ __launch_bounds__(512, 1)
void k_layer(const unsigned short* __restrict__ Abf,  // (4096, KIN) bf16
             const unsigned short* __restrict__ Wbf,  // (32768, KIN) bf16
             const float* __restrict__ bb,            // 32768
             const float* __restrict__ Ws,            // 128*256
             const float* __restrict__ bs,            // 128
             const float* __restrict__ GT,            // 1024 x 4096
             unsigned short* __restrict__ cur_bf,     // layer0 out (bf16, 4096x128)
             float* __restrict__ out1){               // layer1 out (f32, 4096x128)
  __shared__ __align__(16) unsigned short As[2][128*64];
  __shared__ __align__(16) unsigned short Bs[2][256*64];
  __shared__ float part[4][128];

  const int tid  = threadIdx.x;
  const int lane = tid & 63;
  const int wid  = tid >> 6;
  const int wm = wid >> 2, wn = wid & 3;
  const int lrow = lane & 15, lk = lane >> 4;

  // XCD-bijective remap (4096 = 512*8, so id&7 is bijective per-XCD chunking)
  const int id    = blockIdx.x;
  const int xcd   = id & 7;
  const int local = id >> 3;                 // 0..511
  const int n     = ((local & 15) << 3) + xcd;   // 16 n-values per XCD
  const int bbase = (local >> 4) << 7;           // 32 b-blocks * 128

  f32x4 zero = {0.f,0.f,0.f,0.f};
  f32x4 acc[4][4];
  #pragma unroll
  for (int i=0;i<4;++i)
    #pragma unroll
    for (int j=0;j<4;++j) acc[i][j] = zero;

  // stage tile kt into buffer buf via global_load_lds.
  // LDS linear: chunk c (16B) at As[buf]+c*8 holds global chunk (c&7)^(row&7) of row c>>3.
  auto STAGE = [&](int buf, int kt){
    #pragma unroll
    for (int i = 0; i < 2; ++i){            // A: 128x64 = 1024 chunks
      int c = i*512 + wid*64 + lane;
      int row = c >> 3, kc = c & 7;
      const unsigned short* s = Abf + (size_t)(bbase+row)*KIN + kt*64 + ((kc ^ (row&7))<<3);
      gload16(s, &As[buf][(i*512 + wid*64)*8]);
    }
    #pragma unroll
    for (int i = 0; i < 4; ++i){            // B: 256x64 = 2048 chunks
      int c = i*512 + wid*64 + lane;
      int row = c >> 3, kc = c & 7;
      const unsigned short* s = Wbf + (size_t)((n<<8)+row)*KIN + kt*64 + ((kc ^ (row&7))<<3);
      gload16(s, &Bs[buf][(i*512 + wid*64)*8]);
    }
  };

  constexpr int NT = KIN/64;
  STAGE(0, 0);
  asm volatile("s_waitcnt vmcnt(0)" ::: "memory");
  __builtin_amdgcn_s_barrier();

  int cur = 0;
  #pragma unroll
  for (int kt = 0; kt < NT; ++kt){
    if (kt + 1 < NT) STAGE(cur^1, kt+1);    // prefetch next tile (in flight during MFMA)
    #pragma unroll
    for (int kk = 0; kk < 2; ++kk){
      short8 a[4], b[4];
      #pragma unroll
      for (int fm = 0; fm < 4; ++fm){
        int m = wm*64 + fm*16 + lrow;
        int idx = (m*64 + kk*32 + lk*8) ^ ((m & 7) << 3);
        a[fm] = *(const short8*)(&As[cur][idx]);
      }
      #pragma unroll
      for (int fn = 0; fn < 4; ++fn){
        int r = wn*64 + fn*16 + lrow;
        int idx = (r*64 + kk*32 + lk*8) ^ ((r & 7) << 3);
        b[fn] = *(const short8*)(&Bs[cur][idx]);
      }
      #pragma unroll
      for (int fm = 0; fm < 4; ++fm)
        #pragma unroll
        for (int fn = 0; fn < 4; ++fn)
          acc[fm][fn] = __builtin_amdgcn_mfma_f32_16x16x32_bf16(a[fm], b[fn], acc[fm][fn], 0, 0, 0);
    }
    if (kt + 1 < NT){
      asm volatile("s_waitcnt vmcnt(0)" ::: "memory");  // next tile landed
      __builtin_amdgcn_s_barrier();                      // publish to all waves
      cur ^= 1;
    }
  }

  // ---- epilogue: relu(+bb) * gate * Ws, reduce 256 cols -> out[b,n] ----
  const int gidx = LAYER*512 + n*4 + wn;      // wn == k
  float bbv[4], wsv[4];
  #pragma unroll
  for (int fn = 0; fn < 4; ++fn){
    int c = wn*64 + fn*16 + lrow;
    bbv[fn] = bb[n*256 + c];
    wsv[fn] = Ws[n*256 + c];
  }
  #pragma unroll
  for (int fm = 0; fm < 4; ++fm){
    float4 g = *(const float4*)(GT + (size_t)gidx*4096 + bbase + wm*64 + fm*16 + lk*4);
    float gr[4] = {g.x, g.y, g.z, g.w};
    #pragma unroll
    for (int reg = 0; reg < 4; ++reg){
      float s = 0.f;
      #pragma unroll
      for (int fn = 0; fn < 4; ++fn)
        s += fmaxf(acc[fm][fn][reg] + bbv[fn], 0.f) * wsv[fn];
      s *= gr[reg];
      s += __shfl_xor(s, 1);
      s += __shfl_xor(s, 2);
      s += __shfl_xor(s, 4);
      s += __shfl_xor(s, 8);
      if (lrow == 0) part[wn][wm*64 + fm*16 + lk*4 + reg] = s;
    }
  }
  __syncthreads();
  if (tid < 128){
    float v = part[0][tid] + part[1][tid] + part[2][tid] + part[3][tid] + bs[n];
    if (LAYER == 0) cur_bf[(size_t)(bbase+tid)*128 + n] = f2bf(v);
    else            out1[(size_t)(bbase+tid)*128 + n] = v;
  }
}

// ---------- 7. final projection: out = cur1 @ Wout.T + bout ----------
__global__ void k_final(const float* __restrict__ out1, const float* __restrict__ Wout,
                        const float* __restrict__ bout, float* __restrict__ out){
  int t = blockIdx.x*256 + threadIdx.x;
  int b = t >> 7, o = t & 127;
  const float4* cr = (const float4*)(out1 + (size_t)b*128);
  const float4* wr = (const float4*)(Wout + (size_t)o*128);
  float a = 0.f;
  #pragma unroll
  for (int i = 0; i < 32; ++i){
    float4 c = cr[i], w = wr[i];
    a += c.x*w.x + c.y*w.y + c.z*w.z + c.w*w.w;
  }
  out[t] = a + bout[o];
}

// ---------- launch ----------
extern "C" void kernel_launch(void* const* d_in, const int* in_sizes, int n_in,
                              void* d_out, int out_size, void* d_ws, size_t ws_size,
                              hipStream_t stream){
  const float* x    = (const float*)d_in[0];
  const float* ctx  = (const float*)d_in[1];
  const float* Wb0  = (const float*)d_in[2];
  const float* bb0  = (const float*)d_in[3];
  const float* Ws0  = (const float*)d_in[4];
  const float* bs0  = (const float*)d_in[5];
  const float* Wb1  = (const float*)d_in[6];
  const float* bb1  = (const float*)d_in[7];
  const float* Ws1  = (const float*)d_in[8];
  const float* bs1  = (const float*)d_in[9];
  const float* Wout = (const float*)d_in[10];
  const float* bout = (const float*)d_in[11];
  const float* h1w  = (const float*)d_in[12];
  const float* h1b  = (const float*)d_in[13];
  const float* h2w  = (const float*)d_in[14];
  const float* h2b  = (const float*)d_in[15];
  const float* h3w  = (const float*)d_in[16];
  const float* h3b  = (const float*)d_in[17];
  float* out = (float*)d_out;

  char* ws = (char*)d_ws;
  size_t o = 0;
  unsigned short* x_bf  = (unsigned short*)(ws + o); o += (size_t)4096*256*2;
  unsigned short* W0b   = (unsigned short*)(ws + o); o += (size_t)8388608*2;
  unsigned short* W1b   = (unsigned short*)(ws + o); o += (size_t)4194304*2;
  unsigned short* Wg_bf = (unsigned short*)(ws + o); o += (size_t)1024*256*2;
  float* bg   = (float*)(ws + o); o += 1024*4;
  float* hv2  = (float*)(ws + o); o += 256;
  float* GT   = (float*)(ws + o); o += (size_t)1024*4096*4;
  unsigned short* cur_bf = (unsigned short*)(ws + o); o += (size_t)4096*128*2;
  float* out1 = (float*)(ws + o); o += (size_t)4096*128*4;

  k_convert<<<13312, 256, 0, stream>>>(x, Wb0, Wb1, x_bf, W0b, W1b);
  k_hyper<<<1, 64, 0, stream>>>(ctx, h1w, h1b, h2w, h2b, hv2);
  k_gw<<<4112, 256, 0, stream>>>(hv2, h3w, h3b, Wg_bf, bg);
  k_gates<<<dim3(8, 16), 512, 0, stream>>>(Wg_bf, x_bf, bg, GT);
  k_layer<256, 0><<<4096, 512, 0, stream>>>(x_bf, W0b, bb0, Ws0, bs0, GT, cur_bf, out1);
  k_layer<128, 1><<<4096, 512, 0, stream>>>(cur_bf, W1b, bb1, Ws1, bs1, GT, cur_bf, out1);
  k_final<<<2048, 256, 0, stream>>>(out1, Wout, bout, out);
}

// Round 3
// 266.724 us; speedup vs baseline: 1.1626x; 1.1486x over previous
//
#include <hip/hip_runtime.h>

// ---------- problem constants ----------
#define BB   4096   // batch
#define IN_  256
#define NN   128
#define KK   4
#define JJ   64
#define NG   512        // N*K
#define WS_  131072     // IN*NG
#define PER  131584     // WS_+NG
#define TP   263168     // 2*PER
#define OUTD 128

typedef __attribute__((ext_vector_type(8))) short short8;
typedef __attribute__((ext_vector_type(4))) float f32x4;

__device__ __forceinline__ unsigned short f2bf(float f){
  unsigned u = __float_as_uint(f);
  return (unsigned short)((u + 0x7fffu + ((u >> 16) & 1u)) >> 16);
}

__device__ __forceinline__ void gload16(const void* g, void* l){
  __builtin_amdgcn_global_load_lds((const __attribute__((address_space(1))) void*)g,
                                   (__attribute__((address_space(3))) void*)l, 16, 0, 0);
}

// ---------- 1. f32 -> bf16 convert: x, Wb0, Wb1 ----------
#define XE  (4096u*256u)            // 1048576
#define W0E (XE + 8388608u)         // + 128*4*64*256
#define W1E (W0E + 4194304u)        // + 128*4*64*128

__global__ void k_convert(const float* __restrict__ x,
                          const float* __restrict__ w0,
                          const float* __restrict__ w1,
                          unsigned short* __restrict__ xb,
                          unsigned short* __restrict__ w0b,
                          unsigned short* __restrict__ w1b){
  size_t i = ((size_t)blockIdx.x*256 + threadIdx.x)*4;
  if (i >= W1E) return;
  const float* s; unsigned short* d; size_t off;
  if (i < XE)       { s = x;  d = xb;  off = i; }
  else if (i < W0E) { s = w0; d = w0b; off = i - XE; }
  else              { s = w1; d = w1b; off = i - W0E; }
  float4 v = *(const float4*)(s + off);
  ushort4 o;
  o.x = f2bf(v.x); o.y = f2bf(v.y); o.z = f2bf(v.z); o.w = f2bf(v.w);
  *(ushort4*)(d + off) = o;
}

// ---------- 2. hypernet MLP (context -> hv2[64]) ----------
__global__ void k_hyper(const float* __restrict__ ctx,
                        const float* __restrict__ h1w, const float* __restrict__ h1b,
                        const float* __restrict__ h2w, const float* __restrict__ h2b,
                        float* __restrict__ hv2){
  __shared__ float s1[32];
  int t = threadIdx.x;
  if (t < 32){
    float a = h1b[t];
    #pragma unroll 8
    for (int i = 0; i < 64; ++i) a += ctx[i]*h1w[t*64+i];
    s1[t] = fmaxf(a, 0.f);
  }
  __syncthreads();
  float a = h2b[t];
  #pragma unroll 8
  for (int i = 0; i < 32; ++i) a += s1[i]*h2w[t*32+i];
  hv2[t] = fmaxf(a, 0.f);
}

// ---------- 3. gw = hv2 @ h3w.T + h3b  ->  Wg_bf (1024x256 bf16), bg (1024 f32) ----------
__global__ void k_gw(const float* __restrict__ hv2,
                     const float* __restrict__ h3w, const float* __restrict__ h3b,
                     unsigned short* __restrict__ Wg_bf, float* __restrict__ bg){
  int t = threadIdx.x;
  int r = blockIdx.x*64 + (t >> 2);
  int q = t & 3;
  const float4* row = (const float4*)(h3w + (size_t)r*64);
  float a = 0.f;
  #pragma unroll
  for (int i = 0; i < 4; ++i){
    float4 v = row[q*4 + i];
    float4 h = *(const float4*)(hv2 + q*16 + i*4);
    a += v.x*h.x + v.y*h.y + v.z*h.z + v.w*h.w;
  }
  a += __shfl_xor(a, 1);
  a += __shfl_xor(a, 2);
  if (q == 0){
    a += h3b[r];
    if (r < WS_)          Wg_bf[r] = f2bf(a);
    else if (r < PER)     bg[r - WS_] = a;
    else if (r < PER+WS_) Wg_bf[WS_ + (r - PER)] = f2bf(a);
    else                  bg[512 + (r - (PER+WS_))] = a;
  }
}

// ---------- 4. gates GEMM: G_T[m(1024)][b(4096)] = sigmoid(Wg[m]·x[b] + bg[m]) ----------
__global__ __launch_bounds__(512, 1)
void k_gates(const unsigned short* __restrict__ Wg_bf,  // 1024 x 256
             const unsigned short* __restrict__ x_bf,   // 4096 x 256
             const float* __restrict__ bg,              // 1024
             float* __restrict__ GT){                    // 1024 x 4096
  __shared__ __align__(16) unsigned short As[128*64];
  __shared__ __align__(16) unsigned short Bs[256*64];
  const int tid  = threadIdx.x;
  const int lane = tid & 63;
  const int wid  = tid >> 6;
  const int wm = wid >> 2, wn = wid & 3;
  const int lrow = lane & 15, lk = lane >> 4;
  const int m0 = blockIdx.x*128;
  const int b0 = blockIdx.y*256;

  f32x4 zero = {0.f,0.f,0.f,0.f};
  f32x4 acc[4][4];
  #pragma unroll
  for (int i=0;i<4;++i)
    #pragma unroll
    for (int j=0;j<4;++j) acc[i][j] = zero;

  for (int kt = 0; kt < 256/64; ++kt){
    __syncthreads();
    #pragma unroll
    for (int i = 0; i < 2; ++i){
      int c = tid + i*512;
      int row = c >> 3, k8 = c & 7;
      uint4 v = *(const uint4*)(Wg_bf + (size_t)(m0+row)*256 + kt*64 + k8*8);
      int idx = (row*64 + k8*8) ^ ((row & 7) << 3);
      *(uint4*)(&As[idx]) = v;
    }
    #pragma unroll
    for (int i = 0; i < 4; ++i){
      int c = tid + i*512;
      int row = c >> 3, k8 = c & 7;
      uint4 v = *(const uint4*)(x_bf + (size_t)(b0+row)*256 + kt*64 + k8*8);
      int idx = (row*64 + k8*8) ^ ((row & 7) << 3);
      *(uint4*)(&Bs[idx]) = v;
    }
    __syncthreads();
    #pragma unroll
    for (int kk = 0; kk < 2; ++kk){
      short8 a[4], b[4];
      #pragma unroll
      for (int fm = 0; fm < 4; ++fm){
        int m = wm*64 + fm*16 + lrow;
        int idx = (m*64 + kk*32 + lk*8) ^ ((m & 7) << 3);
        a[fm] = *(const short8*)(&As[idx]);
      }
      #pragma unroll
      for (int fn = 0; fn < 4; ++fn){
        int r = wn*64 + fn*16 + lrow;
        int idx = (r*64 + kk*32 + lk*8) ^ ((r & 7) << 3);
        b[fn] = *(const short8*)(&Bs[idx]);
      }
      #pragma unroll
      for (int fm = 0; fm < 4; ++fm)
        #pragma unroll
        for (int fn = 0; fn < 4; ++fn)
          acc[fm][fn] = __builtin_amdgcn_mfma_f32_16x16x32_bf16(a[fm], b[fn], acc[fm][fn], 0, 0, 0);
    }
  }
  #pragma unroll
  for (int fm = 0; fm < 4; ++fm){
    float4 bgv = *(const float4*)(bg + m0 + wm*64 + fm*16 + lk*4);
    float bga[4] = {bgv.x, bgv.y, bgv.z, bgv.w};
    #pragma unroll
    for (int reg = 0; reg < 4; ++reg){
      int m = m0 + wm*64 + fm*16 + lk*4 + reg;
      #pragma unroll
      for (int fn = 0; fn < 4; ++fn){
        int b = b0 + wn*64 + fn*16 + lrow;
        float z = acc[fm][fn][reg] + bga[reg];
        GT[(size_t)m*4096 + b] = 1.f/(1.f + __expf(-z));
      }
    }
  }
}

// ---------- 5/6. fused DANN layer (A-reuse, 16-n pipeline) ----------
// out[b,n] = sum_{k,j} relu(A[b]·Wb[n,k,j] + bb[n,k,j]) * gate[b,n,k] * Ws[n,k*64+j] + bs[n]
// grid 256 = 32 bbase x 8 ngroups. ngroup = id&7 -> XCD affinity: each XCD's
// 16-n Wb slice (2.1 MB L0) stays L2-resident across its 32 blocks.
// A (x tile, all NT K-tiles) staged ONCE; B double-buffered, staged per
// (n,kt), 1-deep prefetch with counted vmcnt: 16 at epilogue-load iters
// (12 misc loads + 4 next-tile), 4 otherwise, 0 only on the final iter.
template<int KIN, int LAYER>
__global__ __launch_bounds__(512, 1)
void k_layer(const unsigned short* __restrict__ Abf,  // (4096, KIN) bf16
             const unsigned short* __restrict__ Wbf,  // (32768, KIN) bf16
             const float* __restrict__ bb,            // 32768
             const float* __restrict__ Ws,            // 128*256
             const float* __restrict__ bs,            // 128
             const float* __restrict__ GT,            // 1024 x 4096
             unsigned short* __restrict__ cur_bf,     // layer0 out (bf16, 4096x128)
             float* __restrict__ out1){               // layer1 out (f32, 4096x128)
  constexpr int NT = KIN/64;
  __shared__ __align__(16) unsigned short As[NT*8192];   // A: NT tiles of 128x64
  __shared__ __align__(16) unsigned short Bs[2][16384];  // B: dbuf 256x64
  __shared__ float part[4][128];

  const int tid  = threadIdx.x;
  const int lane = tid & 63;
  const int wid  = tid >> 6;
  const int wm = wid >> 2, wn = wid & 3;
  const int lrow = lane & 15, lk = lane >> 4;

  const int id    = blockIdx.x;
  const int nbase = (id & 7) * 16;          // XCD-affine n-group
  const int bbase = (id >> 3) << 7;         // 32 b-blocks * 128

  f32x4 zero = {0.f,0.f,0.f,0.f};
  f32x4 acc[4][4];
  #pragma unroll
  for (int i=0;i<4;++i)
    #pragma unroll
    for (int j=0;j<4;++j) acc[i][j] = zero;

  // B-tile stage: 256x64 = 2048 16B chunks; linear LDS dest, pre-swizzled src.
  auto STAGE_B = [&](int buf, int n, int kt){
    #pragma unroll
    for (int i = 0; i < 4; ++i){
      int c = i*512 + tid;
      int row = c >> 3, kc = c & 7;
      const unsigned short* s = Wbf + (size_t)((n<<8)+row)*KIN + kt*64 + ((kc ^ (row&7))<<3);
      gload16(s, &Bs[buf][(i*512 + wid*64)*8]);
    }
  };

  // prologue: all A K-tiles + first B tile (latency hidden under iter-0 issue)
  #pragma unroll
  for (int kt = 0; kt < NT; ++kt)
    #pragma unroll
    for (int i = 0; i < 2; ++i){
      int c = i*512 + tid;
      int row = c >> 3, kc = c & 7;
      const unsigned short* s = Abf + (size_t)(bbase+row)*KIN + kt*64 + ((kc ^ (row&7))<<3);
      gload16(s, &As[kt*8192 + (i*512 + wid*64)*8]);
    }
  STAGE_B(0, nbase, 0);
  asm volatile("" ::: "memory");   // pin: prologue loads precede all loop loads

  int buf = 0;
  #pragma unroll 1
  for (int nn = 0; nn < 16; ++nn){
    const int n = nbase + nn;
    float4 gv[4];
    float bbv[4], wsv[4];
    #pragma unroll
    for (int kt = 0; kt < NT; ++kt){
      if (kt == 0){
        // 12 misc VMEM loads (4x dwordx4 + 8x dword), counted in vmcnt(16)
        const int gidx = LAYER*512 + n*4 + wn;
        #pragma unroll
        for (int fm = 0; fm < 4; ++fm)
          gv[fm] = *(const float4*)(GT + (size_t)gidx*4096 + bbase + wm*64 + fm*16 + lk*4);
        #pragma unroll
        for (int fn = 0; fn < 4; ++fn){
          int c = wn*64 + fn*16 + lrow;
          bbv[fn] = bb[n*256 + c];
          wsv[fn] = Ws[n*256 + c];
        }
      }
      const bool lastIter = (nn == 15) && (kt == NT-1);
      if (!lastIter){
        int nb = n, nkt = kt + 1;
        if (nkt == NT){ nkt = 0; nb = n + 1; }
        STAGE_B(buf ^ 1, nb, nkt);
      }
      if (lastIter)     asm volatile("s_waitcnt vmcnt(0)" ::: "memory");
      else if (kt == 0) asm volatile("s_waitcnt vmcnt(16)" ::: "memory");
      else              asm volatile("s_waitcnt vmcnt(4)" ::: "memory");
      __builtin_amdgcn_s_barrier();

      #pragma unroll
      for (int kk = 0; kk < 2; ++kk){
        short8 a[4], b[4];
        #pragma unroll
        for (int fm = 0; fm < 4; ++fm){
          int m = wm*64 + fm*16 + lrow;
          int idx = kt*8192 + ((m*64 + kk*32 + lk*8) ^ ((m & 7) << 3));
          a[fm] = *(const short8*)(&As[idx]);
        }
        #pragma unroll
        for (int fn = 0; fn < 4; ++fn){
          int r = wn*64 + fn*16 + lrow;
          int idx = (r*64 + kk*32 + lk*8) ^ ((r & 7) << 3);
          b[fn] = *(const short8*)(&Bs[buf][idx]);
        }
        #pragma unroll
        for (int fm = 0; fm < 4; ++fm)
          #pragma unroll
          for (int fn = 0; fn < 4; ++fn)
            acc[fm][fn] = __builtin_amdgcn_mfma_f32_16x16x32_bf16(a[fm], b[fn], acc[fm][fn], 0, 0, 0);
      }

      if (kt == NT-1){
        // epilogue partials: relu(+bb)*Ws, gate, 16-lane reduce
        #pragma unroll
        for (int fm = 0; fm < 4; ++fm){
          float gr[4] = {gv[fm].x, gv[fm].y, gv[fm].z, gv[fm].w};
          #pragma unroll
          for (int reg = 0; reg < 4; ++reg){
            float sum = 0.f;
            #pragma unroll
            for (int fn = 0; fn < 4; ++fn)
              sum += fmaxf(acc[fm][fn][reg] + bbv[fn], 0.f) * wsv[fn];
            sum *= gr[reg];
            sum += __shfl_xor(sum, 1);
            sum += __shfl_xor(sum, 2);
            sum += __shfl_xor(sum, 4);
            sum += __shfl_xor(sum, 8);
            if (lrow == 0) part[wn][wm*64 + fm*16 + lk*4 + reg] = sum;
          }
        }
      }
      __builtin_amdgcn_s_barrier();
      if (kt == NT-1){
        if (tid < 128){
          float v = part[0][tid] + part[1][tid] + part[2][tid] + part[3][tid] + bs[n];
          if (LAYER == 0) cur_bf[(size_t)(bbase+tid)*128 + n] = f2bf(v);
          else            out1[(size_t)(bbase+tid)*128 + n] = v;
        }
        #pragma unroll
        for (int i2 = 0; i2 < 4; ++i2)
          #pragma unroll
          for (int j2 = 0; j2 < 4; ++j2) acc[i2][j2] = zero;
      }
      buf ^= 1;
    }
  }
}

// ---------- 7. final projection: out = cur1 @ Wout.T + bout ----------
__global__ void k_final(const float* __restrict__ out1, const float* __restrict__ Wout,
                        const float* __restrict__ bout, float* __restrict__ out){
  int t = blockIdx.x*256 + threadIdx.x;
  int b = t >> 7, o = t & 127;
  const float4* cr = (const float4*)(out1 + (size_t)b*128);
  const float4* wr = (const float4*)(Wout + (size_t)o*128);
  float a = 0.f;
  #pragma unroll
  for (int i = 0; i < 32; ++i){
    float4 c = cr[i], w = wr[i];
    a += c.x*w.x + c.y*w.y + c.z*w.z + c.w*w.w;
  }
  out[t] = a + bout[o];
}

// ---------- launch ----------
extern "C" void kernel_launch(void* const* d_in, const int* in_sizes, int n_in,
                              void* d_out, int out_size, void* d_ws, size_t ws_size,
                              hipStream_t stream){
  const float* x    = (const float*)d_in[0];
  const float* ctx  = (const float*)d_in[1];
  const float* Wb0  = (const float*)d_in[2];
  const float* bb0  = (const float*)d_in[3];
  const float* Ws0  = (const float*)d_in[4];
  const float* bs0  = (const float*)d_in[5];
  const float* Wb1  = (const float*)d_in[6];
  const float* bb1  = (const float*)d_in[7];
  const float* Ws1  = (const float*)d_in[8];
  const float* bs1  = (const float*)d_in[9];
  const float* Wout = (const float*)d_in[10];
  const float* bout = (const float*)d_in[11];
  const float* h1w  = (const float*)d_in[12];
  const float* h1b  = (const float*)d_in[13];
  const float* h2w  = (const float*)d_in[14];
  const float* h2b  = (const float*)d_in[15];
  const float* h3w  = (const float*)d_in[16];
  const float* h3b  = (const float*)d_in[17];
  float* out = (float*)d_out;

  char* ws = (char*)d_ws;
  size_t o = 0;
  unsigned short* x_bf  = (unsigned short*)(ws + o); o += (size_t)4096*256*2;
  unsigned short* W0b   = (unsigned short*)(ws + o); o += (size_t)8388608*2;
  unsigned short* W1b   = (unsigned short*)(ws + o); o += (size_t)4194304*2;
  unsigned short* Wg_bf = (unsigned short*)(ws + o); o += (size_t)1024*256*2;
  float* bg   = (float*)(ws + o); o += 1024*4;
  float* hv2  = (float*)(ws + o); o += 256;
  float* GT   = (float*)(ws + o); o += (size_t)1024*4096*4;
  unsigned short* cur_bf = (unsigned short*)(ws + o); o += (size_t)4096*128*2;
  float* out1 = (float*)(ws + o); o += (size_t)4096*128*4;

  k_convert<<<13312, 256, 0, stream>>>(x, Wb0, Wb1, x_bf, W0b, W1b);
  k_hyper<<<1, 64, 0, stream>>>(ctx, h1w, h1b, h2w, h2b, hv2);
  k_gw<<<4112, 256, 0, stream>>>(hv2, h3w, h3b, Wg_bf, bg);
  k_gates<<<dim3(8, 16), 512, 0, stream>>>(Wg_bf, x_bf, bg, GT);
  k_layer<256, 0><<<256, 512, 0, stream>>>(x_bf, W0b, bb0, Ws0, bs0, GT, cur_bf, out1);
  k_layer<128, 1><<<256, 512, 0, stream>>>(cur_bf, W1b, bb1, Ws1, bs1, GT, cur_bf, out1);
  k_final<<<2048, 256, 0, stream>>>(out1, Wout, bout, out);
}